// Round 5
// baseline (781.782 us; speedup 1.0000x reference)
//
#include <hip/hip_runtime.h>

#define NB   16
#define NC   64
#define NPTS 65536
#define RES  32
#define R3   32768
#define PPB  2048   // points per block in reduction kernels (32 blocks/batch)

// ---------------- K1: partial sums for per-batch coord mean ----------------
__global__ void mean_partial(const float* __restrict__ coords, float* __restrict__ meanacc) {
    int bid = blockIdx.x;
    int b = bid >> 5, chunk = bid & 31;
    const float* cb = coords + (size_t)b * 3 * NPTS + chunk * PPB;
    float s0 = 0.f, s1 = 0.f, s2 = 0.f;
    for (int i = threadIdx.x; i < PPB; i += 256) {
        s0 += cb[i];
        s1 += cb[NPTS + i];
        s2 += cb[2 * NPTS + i];
    }
    for (int off = 32; off > 0; off >>= 1) {
        s0 += __shfl_down(s0, off);
        s1 += __shfl_down(s1, off);
        s2 += __shfl_down(s2, off);
    }
    if ((threadIdx.x & 63) == 0) {
        atomicAdd(&meanacc[b * 3 + 0], s0);
        atomicAdd(&meanacc[b * 3 + 1], s1);
        atomicAdd(&meanacc[b * 3 + 2], s2);
    }
}

// ---------------- K2: per-batch max L2 norm (atomicMax on int-reinterpreted float) ----------------
__global__ void maxnorm_partial(const float* __restrict__ coords,
                                const float* __restrict__ meanacc,
                                int* __restrict__ maxn) {
    int bid = blockIdx.x;
    int b = bid >> 5, chunk = bid & 31;
    const float* cb = coords + (size_t)b * 3 * NPTS + chunk * PPB;
    float m0 = meanacc[b * 3 + 0] * (1.0f / NPTS);
    float m1 = meanacc[b * 3 + 1] * (1.0f / NPTS);
    float m2 = meanacc[b * 3 + 2] * (1.0f / NPTS);
    float mx = 0.f;
    for (int i = threadIdx.x; i < PPB; i += 256) {
        float x = cb[i] - m0;
        float y = cb[NPTS + i] - m1;
        float z = cb[2 * NPTS + i] - m2;
        mx = fmaxf(mx, sqrtf(x * x + y * y + z * z));
    }
    for (int off = 32; off > 0; off >>= 1)
        mx = fmaxf(mx, __shfl_down(mx, off));
    if ((threadIdx.x & 63) == 0)
        atomicMax(&maxn[b], __float_as_int(mx));   // norms >= 0: int order == float order
}

// ---------------- K3: normalize coords (2nd output), voxel id, count histogram ----------------
__global__ void voxelize(const float* __restrict__ coords,
                         const float* __restrict__ meanacc,
                         const int* __restrict__ maxn,
                         float* __restrict__ ncout,
                         unsigned short* __restrict__ voxid,
                         unsigned int* __restrict__ cnt) {
    int t = blockIdx.x * 256 + threadIdx.x;
    int b = t >> 16, n = t & (NPTS - 1);
    const float* cb = coords + (size_t)b * 3 * NPTS;
    float m2 = __int_as_float(maxn[b]) * 2.0f;   // EPS = 0
    float c0 = meanacc[b * 3 + 0] * (1.0f / NPTS);
    float c1 = meanacc[b * 3 + 1] * (1.0f / NPTS);
    float c2 = meanacc[b * 3 + 2] * (1.0f / NPTS);
    float ncx = (cb[n]            - c0) / m2 + 0.5f;
    float ncy = (cb[NPTS + n]     - c1) / m2 + 0.5f;
    float ncz = (cb[2 * NPTS + n] - c2) / m2 + 0.5f;
    float sx = fminf(fmaxf(ncx * (float)RES, 0.f), (float)(RES - 1));
    float sy = fminf(fmaxf(ncy * (float)RES, 0.f), (float)(RES - 1));
    float sz = fminf(fmaxf(ncz * (float)RES, 0.f), (float)(RES - 1));
    float* nb = ncout + (size_t)b * 3 * NPTS;
    nb[n]            = sx;
    nb[NPTS + n]     = sy;
    nb[2 * NPTS + n] = sz;
    int v = (((int)rintf(sx)) << 10) + (((int)rintf(sy)) << 5) + (int)rintf(sz);
    voxid[t] = (unsigned short)v;
    atomicAdd(&cnt[((size_t)b << 15) + v], 1u);
}

// ---------------- K4: fused scatter-mean via per-(b,c) LDS grid slice ----------------
// One block per (batch, channel): the 32x32x32 grid slice for one channel is
// 32768 floats = 128 KB -> lives entirely in LDS. Stream the channel's 65536
// features (float4, coalesced) + shared voxid (ushort4, L2-resident after the
// first block of the batch touches it), LDS-atomicAdd into the slice (hot
// gaussian voxel ~100 pts/block -> ~0.1 same-address lanes per wave instr,
// negligible serialization), then write the slice out coalesced dividing by
// cnt (L2-resident). Empty voxels: acc=0, cnt=0 -> 0. No grid memset needed,
// no sorted intermediate, no global atomics on the grid.
__global__ __launch_bounds__(1024) void lds_grid(const float* __restrict__ features,
                                                 const unsigned short* __restrict__ voxid,
                                                 const unsigned int* __restrict__ cnt,
                                                 float* __restrict__ grid) {
    extern __shared__ float acc[];           // 32768 floats = 128 KB
    int b = blockIdx.x >> 6, c = blockIdx.x & 63;
    for (int i = threadIdx.x; i < R3; i += 1024)
        acc[i] = 0.f;
    __syncthreads();
    const float4*  f4 = (const float4*)(features + ((size_t)((b << 6) + c) << 16));
    const ushort4* v4 = (const ushort4*)(voxid + ((size_t)b << 16));
    for (int i = threadIdx.x; i < (NPTS >> 2); i += 1024) {   // 16 iters/thread
        float4  fv = f4[i];
        ushort4 vv = v4[i];
        atomicAdd(&acc[vv.x], fv.x);
        atomicAdd(&acc[vv.y], fv.y);
        atomicAdd(&acc[vv.z], fv.z);
        atomicAdd(&acc[vv.w], fv.w);
    }
    __syncthreads();
    const unsigned int* cb = cnt + ((size_t)b << 15);
    float* g = grid + ((size_t)((b << 6) + c) << 15);
    for (int v = threadIdx.x; v < R3; v += 1024)
        g[v] = acc[v] / fmaxf((float)cb[v], 1.0f);
}

extern "C" void kernel_launch(void* const* d_in, const int* in_sizes, int n_in,
                              void* d_out, int out_size, void* d_ws, size_t ws_size,
                              hipStream_t stream) {
    const float* features = (const float*)d_in[0];  // [16, 64, 65536]
    const float* coords   = (const float*)d_in[1];  // [16, 3, 65536]

    float* grid  = (float*)d_out;                    // [16, 64, 32768]
    float* ncout = grid + (size_t)NB * NC * R3;      // [16, 3, 65536]

    // ws: meanacc[48] | maxn[16] | pad->256B | cnt 2MB | voxid 2MB(u16)
    char* base = (char*)d_ws;
    float* meanacc = (float*)base;
    int*   maxn    = (int*)(base + 192);
    unsigned int*   cnt   = (unsigned int*)(base + 256);
    unsigned short* voxid = (unsigned short*)(cnt + (size_t)NB * R3);

    // zero meanacc/maxn/cnt (~2 MB)
    hipMemsetAsync(d_ws, 0, 256 + (size_t)NB * R3 * sizeof(unsigned int), stream);

    mean_partial   <<<NB * 32, 256, 0, stream>>>(coords, meanacc);
    maxnorm_partial<<<NB * 32, 256, 0, stream>>>(coords, meanacc, maxn);
    voxelize       <<<NB * NPTS / 256, 256, 0, stream>>>(coords, meanacc, maxn, ncout, voxid, cnt);
    lds_grid       <<<NB * NC, 1024, R3 * sizeof(float), stream>>>(features, voxid, cnt, grid);
}

// Round 6
// 536.634 us; speedup vs baseline: 1.4568x; 1.4568x over previous
//
#include <hip/hip_runtime.h>

#define NB   16
#define NC   64
#define NPTS 65536
#define RES  32
#define R3   32768
#define PPB  2048   // points per block in reduction kernels (32 blocks/batch)

// ---------------- K1: partial sums for per-batch coord mean ----------------
__global__ void mean_partial(const float* __restrict__ coords, float* __restrict__ meanacc) {
    int bid = blockIdx.x;
    int b = bid >> 5, chunk = bid & 31;
    const float* cb = coords + (size_t)b * 3 * NPTS + chunk * PPB;
    float s0 = 0.f, s1 = 0.f, s2 = 0.f;
    for (int i = threadIdx.x; i < PPB; i += 256) {
        s0 += cb[i];
        s1 += cb[NPTS + i];
        s2 += cb[2 * NPTS + i];
    }
    for (int off = 32; off > 0; off >>= 1) {
        s0 += __shfl_down(s0, off);
        s1 += __shfl_down(s1, off);
        s2 += __shfl_down(s2, off);
    }
    if ((threadIdx.x & 63) == 0) {
        atomicAdd(&meanacc[b * 3 + 0], s0);
        atomicAdd(&meanacc[b * 3 + 1], s1);
        atomicAdd(&meanacc[b * 3 + 2], s2);
    }
}

// ---------------- K2: per-batch max L2 norm (atomicMax on int-reinterpreted float) ----------------
__global__ void maxnorm_partial(const float* __restrict__ coords,
                                const float* __restrict__ meanacc,
                                int* __restrict__ maxn) {
    int bid = blockIdx.x;
    int b = bid >> 5, chunk = bid & 31;
    const float* cb = coords + (size_t)b * 3 * NPTS + chunk * PPB;
    float m0 = meanacc[b * 3 + 0] * (1.0f / NPTS);
    float m1 = meanacc[b * 3 + 1] * (1.0f / NPTS);
    float m2 = meanacc[b * 3 + 2] * (1.0f / NPTS);
    float mx = 0.f;
    for (int i = threadIdx.x; i < PPB; i += 256) {
        float x = cb[i] - m0;
        float y = cb[NPTS + i] - m1;
        float z = cb[2 * NPTS + i] - m2;
        mx = fmaxf(mx, sqrtf(x * x + y * y + z * z));
    }
    for (int off = 32; off > 0; off >>= 1)
        mx = fmaxf(mx, __shfl_down(mx, off));
    if ((threadIdx.x & 63) == 0)
        atomicMax(&maxn[b], __float_as_int(mx));   // norms >= 0: int order == float order
}

// ---------------- K3: normalize coords (2nd output), voxel id, count histogram ----------------
__global__ void voxelize(const float* __restrict__ coords,
                         const float* __restrict__ meanacc,
                         const int* __restrict__ maxn,
                         float* __restrict__ ncout,
                         unsigned short* __restrict__ voxid,
                         unsigned int* __restrict__ cnt) {
    int t = blockIdx.x * 256 + threadIdx.x;
    int b = t >> 16, n = t & (NPTS - 1);
    const float* cb = coords + (size_t)b * 3 * NPTS;
    float m2 = __int_as_float(maxn[b]) * 2.0f;   // EPS = 0
    float c0 = meanacc[b * 3 + 0] * (1.0f / NPTS);
    float c1 = meanacc[b * 3 + 1] * (1.0f / NPTS);
    float c2 = meanacc[b * 3 + 2] * (1.0f / NPTS);
    float ncx = (cb[n]            - c0) / m2 + 0.5f;
    float ncy = (cb[NPTS + n]     - c1) / m2 + 0.5f;
    float ncz = (cb[2 * NPTS + n] - c2) / m2 + 0.5f;
    float sx = fminf(fmaxf(ncx * (float)RES, 0.f), (float)(RES - 1));
    float sy = fminf(fmaxf(ncy * (float)RES, 0.f), (float)(RES - 1));
    float sz = fminf(fmaxf(ncz * (float)RES, 0.f), (float)(RES - 1));
    float* nb = ncout + (size_t)b * 3 * NPTS;
    nb[n]            = sx;
    nb[NPTS + n]     = sy;
    nb[2 * NPTS + n] = sz;
    int v = (((int)rintf(sx)) << 10) + (((int)rintf(sy)) << 5) + (int)rintf(sz);
    voxid[t] = (unsigned short)v;
    atomicAdd(&cnt[((size_t)b << 15) + v], 1u);
}

// ---------------- K4: fused scatter-mean via per-(b,c) LDS grid slice ----------------
// One block per (batch, channel): the 32x32x32 grid slice for one channel is
// 32768 x 4B -> lives entirely in LDS. Accumulate in FIXED-POINT int (scale
// 2^16): atomicAdd(int*) lowers to native ds_add_u32 (single DS instr, no
// CAS-retry loop), unlike float atomicAdd which ROCm lowers to a CAS loop
// (the 218 cyc/atomic observed in round 5). Range: |f|<~6 -> |f*2^16| < 4e5;
// hot voxel ~100 pts -> |sum| < 2e7 << 2^31. Quantization ~7.6e-6/pt, far
// below the bf16 error already accepted. Epilogue divides by 2^16 * cnt.
__global__ __launch_bounds__(1024) void lds_grid(const float* __restrict__ features,
                                                 const unsigned short* __restrict__ voxid,
                                                 const unsigned int* __restrict__ cnt,
                                                 float* __restrict__ grid) {
    extern __shared__ int acc[];             // 32768 ints = 128 KB
    int b = blockIdx.x >> 6, c = blockIdx.x & 63;
    for (int i = threadIdx.x; i < R3; i += 1024)
        acc[i] = 0;
    __syncthreads();
    const float4*  f4 = (const float4*)(features + ((size_t)((b << 6) + c) << 16));
    const ushort4* v4 = (const ushort4*)(voxid + ((size_t)b << 16));
    for (int i = threadIdx.x; i < (NPTS >> 2); i += 1024) {   // 16 iters/thread
        float4  fv = f4[i];
        ushort4 vv = v4[i];
        atomicAdd(&acc[vv.x], (int)rintf(fv.x * 65536.0f));
        atomicAdd(&acc[vv.y], (int)rintf(fv.y * 65536.0f));
        atomicAdd(&acc[vv.z], (int)rintf(fv.z * 65536.0f));
        atomicAdd(&acc[vv.w], (int)rintf(fv.w * 65536.0f));
    }
    __syncthreads();
    const unsigned int* cb = cnt + ((size_t)b << 15);
    float* g = grid + ((size_t)((b << 6) + c) << 15);
    for (int v = threadIdx.x; v < R3; v += 1024)
        g[v] = (float)acc[v] * (1.0f / 65536.0f) / fmaxf((float)cb[v], 1.0f);
}

extern "C" void kernel_launch(void* const* d_in, const int* in_sizes, int n_in,
                              void* d_out, int out_size, void* d_ws, size_t ws_size,
                              hipStream_t stream) {
    const float* features = (const float*)d_in[0];  // [16, 64, 65536]
    const float* coords   = (const float*)d_in[1];  // [16, 3, 65536]

    float* grid  = (float*)d_out;                    // [16, 64, 32768]
    float* ncout = grid + (size_t)NB * NC * R3;      // [16, 3, 65536]

    // ws: meanacc[48] | maxn[16] | pad->256B | cnt 2MB | voxid 2MB(u16)
    char* base = (char*)d_ws;
    float* meanacc = (float*)base;
    int*   maxn    = (int*)(base + 192);
    unsigned int*   cnt   = (unsigned int*)(base + 256);
    unsigned short* voxid = (unsigned short*)(cnt + (size_t)NB * R3);

    // zero meanacc/maxn/cnt (~2 MB)
    hipMemsetAsync(d_ws, 0, 256 + (size_t)NB * R3 * sizeof(unsigned int), stream);

    mean_partial   <<<NB * 32, 256, 0, stream>>>(coords, meanacc);
    maxnorm_partial<<<NB * 32, 256, 0, stream>>>(coords, meanacc, maxn);
    voxelize       <<<NB * NPTS / 256, 256, 0, stream>>>(coords, meanacc, maxn, ncout, voxid, cnt);
    lds_grid       <<<NB * NC, 1024, R3 * sizeof(int), stream>>>(features, voxid, cnt, grid);
}

// Round 8
// 517.690 us; speedup vs baseline: 1.5101x; 1.0366x over previous
//
#include <hip/hip_runtime.h>

#define NB   16
#define NC   64
#define NPTS 65536
#define RES  32
#define R3   32768
#define PPB  2048   // points per block in reduction kernels (32 blocks/batch)

typedef float fx4 __attribute__((ext_vector_type(4)));   // clang-native for nontemporal builtins
typedef int   ix4 __attribute__((ext_vector_type(4)));

// ---------------- K1: partial sums for per-batch coord mean ----------------
__global__ void mean_partial(const float* __restrict__ coords, float* __restrict__ meanacc) {
    int bid = blockIdx.x;
    int b = bid >> 5, chunk = bid & 31;
    const float* cb = coords + (size_t)b * 3 * NPTS + chunk * PPB;
    float s0 = 0.f, s1 = 0.f, s2 = 0.f;
    for (int i = threadIdx.x; i < PPB; i += 256) {
        s0 += cb[i];
        s1 += cb[NPTS + i];
        s2 += cb[2 * NPTS + i];
    }
    for (int off = 32; off > 0; off >>= 1) {
        s0 += __shfl_down(s0, off);
        s1 += __shfl_down(s1, off);
        s2 += __shfl_down(s2, off);
    }
    if ((threadIdx.x & 63) == 0) {
        atomicAdd(&meanacc[b * 3 + 0], s0);
        atomicAdd(&meanacc[b * 3 + 1], s1);
        atomicAdd(&meanacc[b * 3 + 2], s2);
    }
}

// ---------------- K2: per-batch max L2 norm (atomicMax on int-reinterpreted float) ----------------
__global__ void maxnorm_partial(const float* __restrict__ coords,
                                const float* __restrict__ meanacc,
                                int* __restrict__ maxn) {
    int bid = blockIdx.x;
    int b = bid >> 5, chunk = bid & 31;
    const float* cb = coords + (size_t)b * 3 * NPTS + chunk * PPB;
    float m0 = meanacc[b * 3 + 0] * (1.0f / NPTS);
    float m1 = meanacc[b * 3 + 1] * (1.0f / NPTS);
    float m2 = meanacc[b * 3 + 2] * (1.0f / NPTS);
    float mx = 0.f;
    for (int i = threadIdx.x; i < PPB; i += 256) {
        float x = cb[i] - m0;
        float y = cb[NPTS + i] - m1;
        float z = cb[2 * NPTS + i] - m2;
        mx = fmaxf(mx, sqrtf(x * x + y * y + z * z));
    }
    for (int off = 32; off > 0; off >>= 1)
        mx = fmaxf(mx, __shfl_down(mx, off));
    if ((threadIdx.x & 63) == 0)
        atomicMax(&maxn[b], __float_as_int(mx));   // norms >= 0: int order == float order
}

// ---------------- K3: normalize coords (2nd output), voxel id, count histogram ----------------
__global__ void voxelize(const float* __restrict__ coords,
                         const float* __restrict__ meanacc,
                         const int* __restrict__ maxn,
                         float* __restrict__ ncout,
                         unsigned short* __restrict__ voxid,
                         unsigned int* __restrict__ cnt) {
    int t = blockIdx.x * 256 + threadIdx.x;
    int b = t >> 16, n = t & (NPTS - 1);
    const float* cb = coords + (size_t)b * 3 * NPTS;
    float m2 = __int_as_float(maxn[b]) * 2.0f;   // EPS = 0
    float c0 = meanacc[b * 3 + 0] * (1.0f / NPTS);
    float c1 = meanacc[b * 3 + 1] * (1.0f / NPTS);
    float c2 = meanacc[b * 3 + 2] * (1.0f / NPTS);
    float ncx = (cb[n]            - c0) / m2 + 0.5f;
    float ncy = (cb[NPTS + n]     - c1) / m2 + 0.5f;
    float ncz = (cb[2 * NPTS + n] - c2) / m2 + 0.5f;
    float sx = fminf(fmaxf(ncx * (float)RES, 0.f), (float)(RES - 1));
    float sy = fminf(fmaxf(ncy * (float)RES, 0.f), (float)(RES - 1));
    float sz = fminf(fmaxf(ncz * (float)RES, 0.f), (float)(RES - 1));
    float* nb = ncout + (size_t)b * 3 * NPTS;
    nb[n]            = sx;
    nb[NPTS + n]     = sy;
    nb[2 * NPTS + n] = sz;
    int v = (((int)rintf(sx)) << 10) + (((int)rintf(sy)) << 5) + (int)rintf(sz);
    voxid[t] = (unsigned short)v;
    atomicAdd(&cnt[((size_t)b << 15) + v], 1u);
}

// ---------------- K3b: precompute per-voxel inverse (folds the 2^-16 fixed-point scale) ----------------
// Done once per (b,v) instead of 64x redundantly in every channel block's epilogue.
__global__ void inv_cnt(const unsigned int* __restrict__ cnt, float* __restrict__ invc) {
    int i = blockIdx.x * 256 + threadIdx.x;          // 512K entries
    invc[i] = 1.0f / (65536.0f * fmaxf((float)cnt[i], 1.0f));
}

// ---------------- K4: fused scatter-mean via per-(b,c) LDS grid slice ----------------
// One block per (batch, channel); the channel's 32x32x32 slice (32768 x 4B =
// 128 KB) lives in LDS. Fixed-point int accumulate -> native ds_add_u32
// (round-6 win: no FP-CAS loop). This round: software-pipelined stream loop
// (next fx4/ushort4 loads in flight during current converts+atomics),
// nontemporal feature loads (single-use stream; voxid stays cached - reused
// by 64 blocks/batch), vectorized init and epilogue, and the epilogue
// multiplies by the precomputed invc instead of an int->float divide.
__global__ __launch_bounds__(1024) void lds_grid(const float* __restrict__ features,
                                                 const unsigned short* __restrict__ voxid,
                                                 const float* __restrict__ invc,
                                                 float* __restrict__ grid) {
    extern __shared__ int acc[];             // 32768 ints = 128 KB
    int b = blockIdx.x >> 6, c = blockIdx.x & 63;
    ix4* a4 = (ix4*)acc;
    for (int i = threadIdx.x; i < (R3 >> 2); i += 1024)
        a4[i] = (ix4){0, 0, 0, 0};
    __syncthreads();
    const fx4*     f4 = (const fx4*)(features + ((size_t)((b << 6) + c) << 16));
    const ushort4* v4 = (const ushort4*)(voxid + ((size_t)b << 16));
    fx4     fv = __builtin_nontemporal_load(&f4[threadIdx.x]);
    ushort4 vv = v4[threadIdx.x];
#pragma unroll
    for (int j = 0; j < 16; ++j) {           // 16384 fx4 rows / 1024 threads
        fx4     fn;
        ushort4 vn;
        if (j < 15) {
            fn = __builtin_nontemporal_load(&f4[threadIdx.x + ((j + 1) << 10)]);
            vn = v4[threadIdx.x + ((j + 1) << 10)];
        }
        atomicAdd(&acc[vv.x], (int)rintf(fv.x * 65536.0f));
        atomicAdd(&acc[vv.y], (int)rintf(fv.y * 65536.0f));
        atomicAdd(&acc[vv.z], (int)rintf(fv.z * 65536.0f));
        atomicAdd(&acc[vv.w], (int)rintf(fv.w * 65536.0f));
        fv = fn;
        vv = vn;
    }
    __syncthreads();
    const fx4* ic4 = (const fx4*)(invc + ((size_t)b << 15));
    fx4* g4 = (fx4*)(grid + ((size_t)((b << 6) + c) << 15));
    for (int i = threadIdx.x; i < (R3 >> 2); i += 1024) {
        ix4 a  = a4[i];
        fx4 ic = ic4[i];
        fx4 o;
        o.x = (float)a.x * ic.x;
        o.y = (float)a.y * ic.y;
        o.z = (float)a.z * ic.z;
        o.w = (float)a.w * ic.w;
        __builtin_nontemporal_store(o, &g4[i]);
    }
}

extern "C" void kernel_launch(void* const* d_in, const int* in_sizes, int n_in,
                              void* d_out, int out_size, void* d_ws, size_t ws_size,
                              hipStream_t stream) {
    const float* features = (const float*)d_in[0];  // [16, 64, 65536]
    const float* coords   = (const float*)d_in[1];  // [16, 3, 65536]

    float* grid  = (float*)d_out;                    // [16, 64, 32768]
    float* ncout = grid + (size_t)NB * NC * R3;      // [16, 3, 65536]

    // ws: meanacc[48] | maxn[16] | pad->256B | cnt 2MB | voxid 2MB(u16) | invc 2MB
    char* base = (char*)d_ws;
    float* meanacc = (float*)base;
    int*   maxn    = (int*)(base + 192);
    unsigned int*   cnt   = (unsigned int*)(base + 256);
    unsigned short* voxid = (unsigned short*)(cnt + (size_t)NB * R3);
    float*          invc  = (float*)(voxid + (size_t)NB * NPTS);

    // zero meanacc/maxn/cnt (~2 MB)
    hipMemsetAsync(d_ws, 0, 256 + (size_t)NB * R3 * sizeof(unsigned int), stream);

    mean_partial   <<<NB * 32, 256, 0, stream>>>(coords, meanacc);
    maxnorm_partial<<<NB * 32, 256, 0, stream>>>(coords, meanacc, maxn);
    voxelize       <<<NB * NPTS / 256, 256, 0, stream>>>(coords, meanacc, maxn, ncout, voxid, cnt);
    inv_cnt        <<<NB * R3 / 256, 256, 0, stream>>>(cnt, invc);
    lds_grid       <<<NB * NC, 1024, R3 * sizeof(int), stream>>>(features, voxid, invc, grid);
}